// Round 3
// baseline (8424.747 us; speedup 1.0000x reference)
//
#include <hip/hip_runtime.h>
#include <stdint.h>

// GRU: L=2, D=H=1024, S=512, B=32.
// Phase 1: xg[s,l,gate,b,h] = x[s,b,:] @ W[l,gate,h,:]^T  (bf16 MFMA GEMM)
// Phase 2: persistent 256-WG recurrence, U-weights LDS-resident.
//   Cross-WG exchange: self-validating 8B lines {u32 epoch | 2 bf16} via
//   agent-scope relaxed atomics (single-copy atomic, no tear). Consumers
//   poll-load; tag match => data valid in the same load. NO barriers, NO
//   counters, NO fences. Lockstep guaranteed by the tag chain.

typedef __attribute__((ext_vector_type(8))) short bf16x8;
typedef __attribute__((ext_vector_type(4))) float f32x4;

#define NL 2
#define SB 32
#define HD 1024
#define SEQ 512

// ---- workspace layout (bytes) ----
#define XG_ELEMS   ((size_t)SEQ*6*SB*HD)
#define XG_OFF     0ull
#define XBF_OFF    (XG_OFF + XG_ELEMS*2)
#define XBF_ELEMS  ((size_t)SEQ*SB*HD)
#define WBF_OFF    (XBF_OFF + XBF_ELEMS*2)
#define WBF_ELEMS  ((size_t)6*HD*HD)
#define HLN_OFF    (WBF_OFF + WBF_ELEMS*2)     // tagged h lines  [L][32][512] u64
#define LN_ELEMS   ((size_t)NL*SB*(HD/2))      // 32768 lines
#define RLN_OFF    (HLN_OFF + LN_ELEMS*8)      // tagged r*h lines
#define WS_NEED    (RLN_OFF + LN_ELEMS*8)

__device__ __forceinline__ unsigned short f2bf(float f) {
  unsigned int u = __float_as_uint(f);
  u = u + 0x7fffu + ((u >> 16) & 1u);
  return (unsigned short)(u >> 16);
}
__device__ __forceinline__ float bf2f(unsigned int bits) {
  return __uint_as_float(bits << 16);
}
__device__ __forceinline__ f32x4 unpack4(uint2 u) {
  f32x4 v;
  v[0] = bf2f(u.x & 0xffffu); v[1] = bf2f(u.x >> 16);
  v[2] = bf2f(u.y & 0xffffu); v[3] = bf2f(u.y >> 16);
  return v;
}

__device__ __forceinline__ unsigned long long ld_wt(const unsigned long long* p) {
  return __hip_atomic_load(p, __ATOMIC_RELAXED, __HIP_MEMORY_SCOPE_AGENT);
}
__device__ __forceinline__ void st_wt(unsigned long long* p, unsigned long long v) {
  __hip_atomic_store(p, v, __ATOMIC_RELAXED, __HIP_MEMORY_SCOPE_AGENT);
}

// ---------------- fp32 -> bf16 convert ----------------
__global__ void cvt_f32_bf16(const float* __restrict__ src,
                             unsigned short* __restrict__ dst, int n4) {
  int i = blockIdx.x * blockDim.x + threadIdx.x;
  int st = gridDim.x * blockDim.x;
  for (; i < n4; i += st) {
    float4 v = ((const float4*)src)[i];
    ushort4 o = { f2bf(v.x), f2bf(v.y), f2bf(v.z), f2bf(v.w) };
    ((ushort4*)dst)[i] = o;
  }
}

// ---------------- phase 1 GEMM ----------------
__global__ __launch_bounds__(256) void gemm_xg(const unsigned short* __restrict__ Wb,
                                               const unsigned short* __restrict__ xb,
                                               unsigned short* __restrict__ xg) {
  __shared__ short As[128 * 32];
  __shared__ short Bs[128 * 32];
  const int lg = blockIdx.z;
  const int m0 = blockIdx.y * 128;
  const int n0 = blockIdx.x * 128;
  const int tid = threadIdx.x, w = tid >> 6, lane = tid & 63;
  const int wm = (w >> 1) * 64, wn = (w & 1) * 64;
  const unsigned short* Ag = Wb + (size_t)lg * HD * HD;

  f32x4 acc[4][4] = {};

  for (int k0 = 0; k0 < HD; k0 += 32) {
    __syncthreads();
#pragma unroll
    for (int i = 0; i < 2; i++) {
      int off = (i * 256 + tid) * 16;
      int rr = off >> 6;
      int cc = (off >> 4) & 3;
      *(uint4*)((char*)As + off) = *(const uint4*)(Ag + (size_t)(m0 + rr) * HD + k0 + cc * 8);
      *(uint4*)((char*)Bs + off) = *(const uint4*)(xb + (size_t)(n0 + rr) * HD + k0 + cc * 8);
    }
    __syncthreads();
    bf16x8 af[4], bf[4];
#pragma unroll
    for (int mi = 0; mi < 4; mi++)
      af[mi] = *(const bf16x8*)&As[(wm + mi * 16 + (lane & 15)) * 32 + ((lane >> 4) << 3)];
#pragma unroll
    for (int ni = 0; ni < 4; ni++)
      bf[ni] = *(const bf16x8*)&Bs[(wn + ni * 16 + (lane & 15)) * 32 + ((lane >> 4) << 3)];
#pragma unroll
    for (int mi = 0; mi < 4; mi++)
#pragma unroll
      for (int ni = 0; ni < 4; ni++)
        acc[mi][ni] = __builtin_amdgcn_mfma_f32_16x16x32_bf16(af[mi], bf[ni], acc[mi][ni], 0, 0, 0);
  }

#pragma unroll
  for (int mi = 0; mi < 4; mi++) {
    int g = m0 + wm + mi * 16 + ((lane >> 4) << 2);
#pragma unroll
    for (int ni = 0; ni < 4; ni++) {
      int n = n0 + wn + ni * 16 + (lane & 15);
      int s = n >> 5, b = n & 31;
      ushort4 o = { f2bf(acc[mi][ni][0]), f2bf(acc[mi][ni][1]),
                    f2bf(acc[mi][ni][2]), f2bf(acc[mi][ni][3]) };
      *(ushort4*)(xg + ((size_t)(s * 6 + lg)) * (SB * HD) + (size_t)b * HD + g) = o;
    }
  }
}

// ---------------- phase 2: recurrence ----------------
__device__ __forceinline__ bf16x8 afrag(const short* wlds, int gate, int lane, int k) {
  int r = lane & 15;
  int kk = k + ((lane >> 4) << 3);
  int ck = (kk >> 3) ^ (r & 7);
  return *(const bf16x8*)&wlds[gate * 16384 + r * HD + (ck << 3)];
}

// publish 4 consecutive h-values (rows g..g+3, g%4==0) as 2 tagged lines
__device__ __forceinline__ void publish(unsigned long long* buf, size_t lcbase,
                                        int g, const f32x4 vals, unsigned tag) {
  unsigned long long* p = buf + lcbase + (g >> 1);
  unsigned d0 = (unsigned)f2bf(vals[0]) | ((unsigned)f2bf(vals[1]) << 16);
  unsigned d1 = (unsigned)f2bf(vals[2]) | ((unsigned)f2bf(vals[3]) << 16);
  st_wt(p,     ((unsigned long long)tag << 32) | d0);
  st_wt(p + 1, ((unsigned long long)tag << 32) | d1);
}

// poll-load 8 bf16x8 fragments (32 tagged lines) until all tags == tag
__device__ __forceinline__ void poll_load(const unsigned long long* base,
                                          unsigned tag, bf16x8* frag) {
  unsigned long long v[32];
  for (;;) {
#pragma unroll
    for (int c = 0; c < 8; c++)
#pragma unroll
      for (int j = 0; j < 4; j++)
        v[c * 4 + j] = ld_wt(base + c * 16 + j);
    bool ok = true;
#pragma unroll
    for (int i = 0; i < 32; i++) ok &= ((unsigned)(v[i] >> 32) == tag);
    if (__all(ok)) break;
  }
#pragma unroll
  for (int c = 0; c < 8; c++) {
    union { unsigned d[4]; bf16x8 b; } u;
#pragma unroll
    for (int j = 0; j < 4; j++) u.d[j] = (unsigned)v[c * 4 + j];
    frag[c] = u.b;
  }
}

__global__ __launch_bounds__(256, 1) void gru_rec(
    const float* __restrict__ h0,
    const float* __restrict__ Uz, const float* __restrict__ Ur, const float* __restrict__ Uh,
    const float* __restrict__ bz, const float* __restrict__ br, const float* __restrict__ bh,
    const unsigned short* __restrict__ xg,
    unsigned long long* __restrict__ hln,
    unsigned long long* __restrict__ rln,
    float* __restrict__ out) {
  __shared__ short wlds[3 * 16 * HD];   // 96 KB bf16 U-slices (1 WG/CU)
  __shared__ f32x4 redv[2][256];        // 8 KB cross-wave reduction

  const int wg = blockIdx.x;
  const int l = wg >> 7;
  const int gs = wg & 63;
  const int g0 = gs * 16;
  const int b0 = ((wg >> 6) & 1) * 16;
  const int tid = threadIdx.x;
  const int w = tid >> 6, lane = tid & 63;
  const int col = lane & 15;
  const int rb = (lane >> 4) << 2;

  // load U slices into LDS (bf16, XOR-swizzled chunks of 8)
  const float* Us[3] = { Uz, Ur, Uh };
#pragma unroll
  for (int gate = 0; gate < 3; gate++) {
    const float* U = Us[gate] + (size_t)l * HD * HD + (size_t)g0 * HD;
    for (int it = 0; it < 8; it++) {
      int chunk = it * 256 + tid;
      int r = chunk >> 7;
      int ck = chunk & 127;
      const float* src = U + (size_t)r * HD + ck * 8;
      float4 a = *(const float4*)src;
      float4 bq = *(const float4*)(src + 4);
      bf16x8 o;
      o[0] = (short)f2bf(a.x); o[1] = (short)f2bf(a.y);
      o[2] = (short)f2bf(a.z); o[3] = (short)f2bf(a.w);
      o[4] = (short)f2bf(bq.x); o[5] = (short)f2bf(bq.y);
      o[6] = (short)f2bf(bq.z); o[7] = (short)f2bf(bq.w);
      int sck = ck ^ (r & 7);
      *(bf16x8*)&wlds[gate * 16384 + r * HD + sck * 8] = o;
    }
  }

  f32x4 vbz = *(const f32x4*)(bz + l * HD + g0 + rb);
  f32x4 vbr = *(const f32x4*)(br + l * HD + g0 + rb);
  f32x4 vbh = *(const f32x4*)(bh + l * HD + g0 + rb);

  // per-(layer,col) line-base index into tagged buffers
  const size_t lcbase = ((size_t)(l * SB + b0 + col)) * (HD / 2);
  const size_t hoff = ((size_t)(l * SB + b0 + col)) * HD;   // fp32 h0/out index
  f32x4 hreg = *(const f32x4*)(h0 + hoff + g0 + rb);

  if (w == 0) publish(hln, lcbase, g0 + rb, hreg, 1u);

  const int kb = w * 256;
  const unsigned long long* hbase = hln + lcbase + (kb >> 1) + ((lane >> 4) << 2);
  const unsigned long long* rbase = rln + lcbase + (kb >> 1) + ((lane >> 4) << 2);

  for (int s = 0; s < SEQ; s++) {
    const unsigned tag = (unsigned)(s + 1);
    uint2 xz2 = {}, xr2 = {}, xh2 = {};
    if (w == 0) {
      size_t xbase = ((size_t)s * 6 + l * 3) * (SB * HD) + (size_t)(b0 + col) * HD + g0 + rb;
      xz2 = *(const uint2*)(xg + xbase);
      xr2 = *(const uint2*)(xg + xbase + SB * HD);
      xh2 = *(const uint2*)(xg + xbase + 2 * SB * HD);
    }

    // ---- phase A: z, r ----
    bf16x8 hf[8];
    poll_load(hbase, tag, hf);
    f32x4 accz = { 0, 0, 0, 0 }, accr = { 0, 0, 0, 0 };
#pragma unroll
    for (int i = 0; i < 8; i++) {
      int k = kb + i * 32;
      accz = __builtin_amdgcn_mfma_f32_16x16x32_bf16(afrag(wlds, 0, lane, k), hf[i], accz, 0, 0, 0);
      accr = __builtin_amdgcn_mfma_f32_16x16x32_bf16(afrag(wlds, 1, lane, k), hf[i], accr, 0, 0, 0);
    }
    redv[0][w * 64 + lane] = accz;
    redv[1][w * 64 + lane] = accr;
    __syncthreads();

    f32x4 z = { 0, 0, 0, 0 };
    if (w == 0) {
      f32x4 sz = redv[0][lane] + redv[0][64 + lane] + redv[0][128 + lane] + redv[0][192 + lane];
      f32x4 sr = redv[1][lane] + redv[1][64 + lane] + redv[1][128 + lane] + redv[1][192 + lane];
      f32x4 xzf = unpack4(xz2), xrf = unpack4(xr2);
      f32x4 rh;
#pragma unroll
      for (int j = 0; j < 4; j++) {
        float za = xzf[j] + vbz[j] + sz[j];
        float ra = xrf[j] + vbr[j] + sr[j];
        z[j] = 1.f / (1.f + __expf(-za));
        rh[j] = (1.f / (1.f + __expf(-ra))) * hreg[j];
      }
      publish(rln, lcbase, g0 + rb, rh, tag);
    }
    __syncthreads();   // keep waves' redv reuse safe (phase B reuses redv[0])

    // ---- phase B: hh, h update ----
    bf16x8 rf[8];
    poll_load(rbase, tag, rf);
    f32x4 acch = { 0, 0, 0, 0 };
#pragma unroll
    for (int i = 0; i < 8; i++) {
      int k = kb + i * 32;
      acch = __builtin_amdgcn_mfma_f32_16x16x32_bf16(afrag(wlds, 2, lane, k), rf[i], acch, 0, 0, 0);
    }
    redv[0][w * 64 + lane] = acch;
    __syncthreads();

    if (w == 0) {
      f32x4 sh = redv[0][lane] + redv[0][64 + lane] + redv[0][128 + lane] + redv[0][192 + lane];
      f32x4 xhf = unpack4(xh2);
#pragma unroll
      for (int j = 0; j < 4; j++) {
        float ha = xhf[j] + vbh[j] + sh[j];
        float e = __expf(2.f * ha);             // tanh via exp
        float hh = 1.f - 2.f / (e + 1.f);
        hreg[j] = (1.f - z[j]) * hreg[j] + z[j] * hh;
      }
      publish(hln, lcbase, g0 + rb, hreg, tag + 1);
      if (l == 1)
        *(f32x4*)(out + (size_t)s * (SB * HD) + (size_t)(b0 + col) * HD + g0 + rb) = hreg;
      if (s == SEQ - 1)
        *(f32x4*)(out + (size_t)SEQ * SB * HD + hoff + g0 + rb) = hreg;
    }
    __syncthreads();   // protect redv[0] before next step's phase A writes
  }
}

extern "C" void kernel_launch(void* const* d_in, const int* in_sizes, int n_in,
                              void* d_out, int out_size, void* d_ws, size_t ws_size,
                              hipStream_t stream) {
  const float* x  = (const float*)d_in[0];
  const float* h0 = (const float*)d_in[1];
  const float* Wz = (const float*)d_in[2];
  const float* Wr = (const float*)d_in[3];
  const float* Wh = (const float*)d_in[4];
  const float* Uz = (const float*)d_in[5];
  const float* Ur = (const float*)d_in[6];
  const float* Uh = (const float*)d_in[7];
  const float* bz = (const float*)d_in[8];
  const float* br = (const float*)d_in[9];
  const float* bh = (const float*)d_in[10];

  char* ws = (char*)d_ws;
  unsigned short* xg   = (unsigned short*)(ws + XG_OFF);
  unsigned short* xbf  = (unsigned short*)(ws + XBF_OFF);
  unsigned short* wbf  = (unsigned short*)(ws + WBF_OFF);
  unsigned long long* hln = (unsigned long long*)(ws + HLN_OFF);
  unsigned long long* rln = (unsigned long long*)(ws + RLN_OFF);

  // clear epoch tags (replay safety)
  hipMemsetAsync(hln, 0, LN_ELEMS * 8, stream);
  hipMemsetAsync(rln, 0, LN_ELEMS * 8, stream);

  cvt_f32_bf16<<<1024, 256, 0, stream>>>(x, xbf, (int)(XBF_ELEMS / 4));
  const float* Wsrc[3] = { Wz, Wr, Wh };
  for (int gate = 0; gate < 3; gate++)
    for (int l = 0; l < 2; l++)
      cvt_f32_bf16<<<512, 256, 0, stream>>>(Wsrc[gate] + (size_t)l * HD * HD,
                                            wbf + ((size_t)(l * 3 + gate)) * HD * HD,
                                            HD * HD / 4);

  gemm_xg<<<dim3(128, 8, 6), 256, 0, stream>>>(wbf, xbf, xg);

  gru_rec<<<256, 256, 0, stream>>>(h0, Uz, Ur, Uh, bz, br, bh,
                                   xg, hln, rln, (float*)d_out);
}

// Round 5
// 6314.884 us; speedup vs baseline: 1.3341x; 1.3341x over previous
//
#include <hip/hip_runtime.h>
#include <stdint.h>

// GRU: L=2, D=H=1024, S=512, B=32.
// Phase 1: xg[s,l,gate,b,h] = x[s,b,:] @ W[l,gate,h,:]^T  (bf16 MFMA GEMM)
// Phase 2: persistent 256-WG recurrence, U-weights LDS-resident.
//   Cross-WG exchange: fire-and-forget tagged 8B lines {u32 epoch | 2 bf16}
//   + per-producer hint flag. Consumer wave polls its 16 producer flags
//   (narrow), then one wide tagged load, retrying only stale lines. No
//   fences, no producer-side waitcnt, no atomic RMW. Lockstep enforced by
//   the tag chain (a producer provably cannot overwrite an epoch that any
//   consumer still needs: publish(tag+1) happens only after this WG fully
//   consumed tag from every producer, and every consumer of our tag
//   published its own tag output before we could have consumed it).

typedef __attribute__((ext_vector_type(8))) short bf16x8;
typedef __attribute__((ext_vector_type(4))) float f32x4;

#define NL 2
#define SB 32
#define HD 1024
#define SEQ 512

// ---- workspace layout (bytes) ----
#define XG_ELEMS   ((size_t)SEQ*6*SB*HD)
#define XG_OFF     0ull
#define XBF_OFF    (XG_OFF + XG_ELEMS*2)
#define XBF_ELEMS  ((size_t)SEQ*SB*HD)
#define WBF_OFF    (XBF_OFF + XBF_ELEMS*2)
#define WBF_ELEMS  ((size_t)6*HD*HD)
#define HLN_OFF    (WBF_OFF + WBF_ELEMS*2)     // tagged h lines [L][32][512] u64
#define LN_ELEMS   ((size_t)NL*SB*(HD/2))
#define RLN_OFF    (HLN_OFF + LN_ELEMS*8)      // tagged r*h lines
#define HFLG_OFF   (RLN_OFF + LN_ELEMS*8)      // 4 grp x 64 prod x 16 u32 (64B stride)
#define FLG_WORDS  (4*64*16)
#define RFLG_OFF   (HFLG_OFF + FLG_WORDS*4)
#define WS_NEED    (RFLG_OFF + FLG_WORDS*4)

__device__ __forceinline__ unsigned short f2bf(float f) {
  unsigned int u = __float_as_uint(f);
  u = u + 0x7fffu + ((u >> 16) & 1u);
  return (unsigned short)(u >> 16);
}
__device__ __forceinline__ float bf2f(unsigned int bits) {
  return __uint_as_float(bits << 16);
}
__device__ __forceinline__ f32x4 unpack4(uint2 u) {
  f32x4 v;
  v[0] = bf2f(u.x & 0xffffu); v[1] = bf2f(u.x >> 16);
  v[2] = bf2f(u.y & 0xffffu); v[3] = bf2f(u.y >> 16);
  return v;
}

__device__ __forceinline__ unsigned long long ld_wt(const unsigned long long* p) {
  return __hip_atomic_load(p, __ATOMIC_RELAXED, __HIP_MEMORY_SCOPE_AGENT);
}
__device__ __forceinline__ void st_wt(unsigned long long* p, unsigned long long v) {
  __hip_atomic_store(p, v, __ATOMIC_RELAXED, __HIP_MEMORY_SCOPE_AGENT);
}
__device__ __forceinline__ unsigned ld_flag(const unsigned* p) {
  return __hip_atomic_load(p, __ATOMIC_RELAXED, __HIP_MEMORY_SCOPE_AGENT);
}
__device__ __forceinline__ void st_flag(unsigned* p, unsigned v) {
  __hip_atomic_store(p, v, __ATOMIC_RELAXED, __HIP_MEMORY_SCOPE_AGENT);
}

// ---------------- fp32 -> bf16 convert ----------------
__global__ void cvt_f32_bf16(const float* __restrict__ src,
                             unsigned short* __restrict__ dst, int n4) {
  int i = blockIdx.x * blockDim.x + threadIdx.x;
  int st = gridDim.x * blockDim.x;
  for (; i < n4; i += st) {
    float4 v = ((const float4*)src)[i];
    ushort4 o = { f2bf(v.x), f2bf(v.y), f2bf(v.z), f2bf(v.w) };
    ((ushort4*)dst)[i] = o;
  }
}

// ---------------- phase 1 GEMM ----------------
__global__ __launch_bounds__(256) void gemm_xg(const unsigned short* __restrict__ Wb,
                                               const unsigned short* __restrict__ xb,
                                               unsigned short* __restrict__ xg) {
  __shared__ short As[128 * 32];
  __shared__ short Bs[128 * 32];
  const int lg = blockIdx.z;
  const int m0 = blockIdx.y * 128;
  const int n0 = blockIdx.x * 128;
  const int tid = threadIdx.x, w = tid >> 6, lane = tid & 63;
  const int wm = (w >> 1) * 64, wn = (w & 1) * 64;
  const unsigned short* Ag = Wb + (size_t)lg * HD * HD;

  f32x4 acc[4][4] = {};

  for (int k0 = 0; k0 < HD; k0 += 32) {
    __syncthreads();
#pragma unroll
    for (int i = 0; i < 2; i++) {
      int off = (i * 256 + tid) * 16;
      int rr = off >> 6;
      int cc = (off >> 4) & 3;
      *(uint4*)((char*)As + off) = *(const uint4*)(Ag + (size_t)(m0 + rr) * HD + k0 + cc * 8);
      *(uint4*)((char*)Bs + off) = *(const uint4*)(xb + (size_t)(n0 + rr) * HD + k0 + cc * 8);
    }
    __syncthreads();
    bf16x8 af[4], bf[4];
#pragma unroll
    for (int mi = 0; mi < 4; mi++)
      af[mi] = *(const bf16x8*)&As[(wm + mi * 16 + (lane & 15)) * 32 + ((lane >> 4) << 3)];
#pragma unroll
    for (int ni = 0; ni < 4; ni++)
      bf[ni] = *(const bf16x8*)&Bs[(wn + ni * 16 + (lane & 15)) * 32 + ((lane >> 4) << 3)];
#pragma unroll
    for (int mi = 0; mi < 4; mi++)
#pragma unroll
      for (int ni = 0; ni < 4; ni++)
        acc[mi][ni] = __builtin_amdgcn_mfma_f32_16x16x32_bf16(af[mi], bf[ni], acc[mi][ni], 0, 0, 0);
  }

#pragma unroll
  for (int mi = 0; mi < 4; mi++) {
    int g = m0 + wm + mi * 16 + ((lane >> 4) << 2);
#pragma unroll
    for (int ni = 0; ni < 4; ni++) {
      int n = n0 + wn + ni * 16 + (lane & 15);
      int s = n >> 5, b = n & 31;
      ushort4 o = { f2bf(acc[mi][ni][0]), f2bf(acc[mi][ni][1]),
                    f2bf(acc[mi][ni][2]), f2bf(acc[mi][ni][3]) };
      *(ushort4*)(xg + ((size_t)(s * 6 + lg)) * (SB * HD) + (size_t)b * HD + g) = o;
    }
  }
}

// ---------------- phase 2: recurrence ----------------
__device__ __forceinline__ bf16x8 afrag(const short* wlds, int gate, int lane, int k) {
  int r = lane & 15;
  int kk = k + ((lane >> 4) << 3);
  int ck = (kk >> 3) ^ (r & 7);
  return *(const bf16x8*)&wlds[gate * 16384 + r * HD + (ck << 3)];
}

// producer: 2 tagged data lines per lane; lane 0 fires the hint flag
__device__ __forceinline__ void publish(unsigned long long* buf, size_t lcbase,
                                        int g, const f32x4 vals, unsigned tag,
                                        unsigned* flagword, int lane) {
  unsigned long long* p = buf + lcbase + (g >> 1);
  unsigned d0 = (unsigned)f2bf(vals[0]) | ((unsigned)f2bf(vals[1]) << 16);
  unsigned d1 = (unsigned)f2bf(vals[2]) | ((unsigned)f2bf(vals[3]) << 16);
  st_wt(p,     ((unsigned long long)tag << 32) | d0);
  st_wt(p + 1, ((unsigned long long)tag << 32) | d1);
  if (lane == 0) st_flag(flagword, tag);
}

// consumer: narrow poll on the 16 producer flags owning this wave's K-chunk
__device__ __forceinline__ void flag_wait(const unsigned* fgrp, int w, int lane,
                                          unsigned tag) {
  bool ok = true;
  do {
    if (lane < 16)
      ok = (ld_flag(&fgrp[(w * 16 + lane) * 16]) >= tag);
  } while (!__all(ok));
}

// one wide tagged load; retry only stale lines
__device__ __forceinline__ void wide_load(const unsigned long long* base,
                                          unsigned tag, bf16x8* frag) {
  unsigned long long v[32];
#pragma unroll
  for (int c = 0; c < 8; c++)
#pragma unroll
    for (int j = 0; j < 4; j++)
      v[c * 4 + j] = ld_wt(base + c * 16 + j);
  for (;;) {
    bool ok = true;
#pragma unroll
    for (int i = 0; i < 32; i++) ok &= ((unsigned)(v[i] >> 32) == tag);
    if (__all(ok)) break;
#pragma unroll
    for (int c = 0; c < 8; c++)
#pragma unroll
      for (int j = 0; j < 4; j++)
        if ((unsigned)(v[c * 4 + j] >> 32) != tag)
          v[c * 4 + j] = ld_wt(base + c * 16 + j);
  }
#pragma unroll
  for (int c = 0; c < 8; c++) {
    union { unsigned d[4]; bf16x8 b; } u;
#pragma unroll
    for (int j = 0; j < 4; j++) u.d[j] = (unsigned)v[c * 4 + j];
    frag[c] = u.b;
  }
}

__global__ __launch_bounds__(256, 1) void gru_rec(
    const float* __restrict__ h0,
    const float* __restrict__ Uz, const float* __restrict__ Ur, const float* __restrict__ Uh,
    const float* __restrict__ bz, const float* __restrict__ br, const float* __restrict__ bh,
    const unsigned short* __restrict__ xg,
    unsigned long long* __restrict__ hln,
    unsigned long long* __restrict__ rln,
    unsigned* __restrict__ hflg,
    unsigned* __restrict__ rflg,
    float* __restrict__ out) {
  __shared__ short wlds[3 * 16 * HD];   // 96 KB bf16 U-slices (1 WG/CU)
  __shared__ f32x4 redva[2][256];       // 8 KB phase-A reduction
  __shared__ f32x4 redvb[256];          // 4 KB phase-B reduction

  const int wg = blockIdx.x;
  const int l = wg >> 7;
  const int gs = wg & 63;
  const int g0 = gs * 16;
  const int b0 = ((wg >> 6) & 1) * 16;
  const int grp = wg >> 6;              // (l, b-half) group id 0..3
  const int tid = threadIdx.x;
  const int w = tid >> 6, lane = tid & 63;
  const int col = lane & 15;
  const int rb = (lane >> 4) << 2;

  unsigned* hf_g = hflg + grp * 64 * 16;
  unsigned* rf_g = rflg + grp * 64 * 16;

  // load U slices into LDS (bf16, XOR-swizzled chunks of 8)
  const float* Us[3] = { Uz, Ur, Uh };
#pragma unroll
  for (int gate = 0; gate < 3; gate++) {
    const float* U = Us[gate] + (size_t)l * HD * HD + (size_t)g0 * HD;
    for (int it = 0; it < 8; it++) {
      int chunk = it * 256 + tid;
      int r = chunk >> 7;
      int ck = chunk & 127;
      const float* src = U + (size_t)r * HD + ck * 8;
      float4 a = *(const float4*)src;
      float4 bq = *(const float4*)(src + 4);
      bf16x8 o;
      o[0] = (short)f2bf(a.x); o[1] = (short)f2bf(a.y);
      o[2] = (short)f2bf(a.z); o[3] = (short)f2bf(a.w);
      o[4] = (short)f2bf(bq.x); o[5] = (short)f2bf(bq.y);
      o[6] = (short)f2bf(bq.z); o[7] = (short)f2bf(bq.w);
      int sck = ck ^ (r & 7);
      *(bf16x8*)&wlds[gate * 16384 + r * HD + sck * 8] = o;
    }
  }
  __syncthreads();   // wlds written by all waves, read by all waves

  f32x4 vbz = *(const f32x4*)(bz + l * HD + g0 + rb);
  f32x4 vbr = *(const f32x4*)(br + l * HD + g0 + rb);
  f32x4 vbh = *(const f32x4*)(bh + l * HD + g0 + rb);

  const size_t lcbase = ((size_t)(l * SB + b0 + col)) * (HD / 2);
  const size_t hoff = ((size_t)(l * SB + b0 + col)) * HD;
  f32x4 hreg = *(const f32x4*)(h0 + hoff + g0 + rb);

  if (w == 0) publish(hln, lcbase, g0 + rb, hreg, 1u, &hf_g[gs * 16], lane);

  const int kb = w * 256;
  const unsigned long long* hbase = hln + lcbase + (kb >> 1) + ((lane >> 4) << 2);
  const unsigned long long* rbase = rln + lcbase + (kb >> 1) + ((lane >> 4) << 2);

  // xg pipeline: current-step values preloaded one step ahead (w0 only)
  uint2 xzc = {}, xrc = {}, xhc = {};
  if (w == 0) {
    size_t xb0 = ((size_t)l * 3) * (SB * HD) + (size_t)(b0 + col) * HD + g0 + rb;
    xzc = *(const uint2*)(xg + xb0);
    xrc = *(const uint2*)(xg + xb0 + SB * HD);
    xhc = *(const uint2*)(xg + xb0 + 2 * SB * HD);
  }
  uint2 xzn = {}, xrn = {}, xhn = {};

  for (int s = 0; s < SEQ; s++) {
    const unsigned tag = (unsigned)(s + 1);

    // ---- phase A: z, r ----
    flag_wait(hf_g, w, lane, tag);
    bf16x8 hf[8];
    wide_load(hbase, tag, hf);
    f32x4 accz = { 0, 0, 0, 0 }, accr = { 0, 0, 0, 0 };
#pragma unroll
    for (int i = 0; i < 8; i++) {
      int k = kb + i * 32;
      accz = __builtin_amdgcn_mfma_f32_16x16x32_bf16(afrag(wlds, 0, lane, k), hf[i], accz, 0, 0, 0);
      accr = __builtin_amdgcn_mfma_f32_16x16x32_bf16(afrag(wlds, 1, lane, k), hf[i], accr, 0, 0, 0);
    }
    redva[0][w * 64 + lane] = accz;
    redva[1][w * 64 + lane] = accr;
    __syncthreads();   // sync1: redva complete

    f32x4 z = { 0, 0, 0, 0 };
    if (w == 0) {
      f32x4 sz = redva[0][lane] + redva[0][64 + lane] + redva[0][128 + lane] + redva[0][192 + lane];
      f32x4 sr = redva[1][lane] + redva[1][64 + lane] + redva[1][128 + lane] + redva[1][192 + lane];
      f32x4 xzf = unpack4(xzc), xrf = unpack4(xrc);
      f32x4 rh;
#pragma unroll
      for (int j = 0; j < 4; j++) {
        float za = xzf[j] + vbz[j] + sz[j];
        float ra = xrf[j] + vbr[j] + sr[j];
        z[j] = 1.f / (1.f + __expf(-za));
        rh[j] = (1.f / (1.f + __expf(-ra))) * hreg[j];
      }
      publish(rln, lcbase, g0 + rb, rh, tag, &rf_g[gs * 16], lane);
      // prefetch next step's xg (overlaps with phase-B exchange latency)
      int sn = (s + 1 < SEQ) ? s + 1 : s;
      size_t xbn = ((size_t)sn * 6 + l * 3) * (SB * HD) + (size_t)(b0 + col) * HD + g0 + rb;
      xzn = *(const uint2*)(xg + xbn);
      xrn = *(const uint2*)(xg + xbn + SB * HD);
      xhn = *(const uint2*)(xg + xbn + 2 * SB * HD);
    }

    // ---- phase B: hh, h update ----
    flag_wait(rf_g, w, lane, tag);
    bf16x8 rf[8];
    wide_load(rbase, tag, rf);
    f32x4 acch = { 0, 0, 0, 0 };
#pragma unroll
    for (int i = 0; i < 8; i++) {
      int k = kb + i * 32;
      acch = __builtin_amdgcn_mfma_f32_16x16x32_bf16(afrag(wlds, 2, lane, k), rf[i], acch, 0, 0, 0);
    }
    redvb[w * 64 + lane] = acch;
    __syncthreads();   // sync2: redvb complete (redva free for next step)

    if (w == 0) {
      f32x4 sh = redvb[lane] + redvb[64 + lane] + redvb[128 + lane] + redvb[192 + lane];
      f32x4 xhf = unpack4(xhc);
#pragma unroll
      for (int j = 0; j < 4; j++) {
        float ha = xhf[j] + vbh[j] + sh[j];
        float e = __expf(2.f * ha);
        float hh = 1.f - 2.f / (e + 1.f);
        hreg[j] = (1.f - z[j]) * hreg[j] + z[j] * hh;
      }
      publish(hln, lcbase, g0 + rb, hreg, tag + 1, &hf_g[gs * 16], lane);
      if (l == 1)   // output stream is LAST layer only
        *(f32x4*)(out + (size_t)s * (SB * HD) + (size_t)(b0 + col) * HD + g0 + rb) = hreg;
      if (s == SEQ - 1)
        *(f32x4*)(out + (size_t)SEQ * SB * HD + hoff + g0 + rb) = hreg;
      xzc = xzn; xrc = xrn; xhc = xhn;
    }
  }
}

extern "C" void kernel_launch(void* const* d_in, const int* in_sizes, int n_in,
                              void* d_out, int out_size, void* d_ws, size_t ws_size,
                              hipStream_t stream) {
  const float* x  = (const float*)d_in[0];
  const float* h0 = (const float*)d_in[1];
  const float* Wz = (const float*)d_in[2];
  const float* Wr = (const float*)d_in[3];
  const float* Wh = (const float*)d_in[4];
  const float* Uz = (const float*)d_in[5];
  const float* Ur = (const float*)d_in[6];
  const float* Uh = (const float*)d_in[7];
  const float* bz = (const float*)d_in[8];
  const float* br = (const float*)d_in[9];
  const float* bh = (const float*)d_in[10];

  char* ws = (char*)d_ws;
  unsigned short* xg   = (unsigned short*)(ws + XG_OFF);
  unsigned short* xbf  = (unsigned short*)(ws + XBF_OFF);
  unsigned short* wbf  = (unsigned short*)(ws + WBF_OFF);
  unsigned long long* hln = (unsigned long long*)(ws + HLN_OFF);

  // clear tags + flags (replay safety): hln, rln, hflg, rflg are contiguous
  hipMemsetAsync(hln, 0, LN_ELEMS * 16 + FLG_WORDS * 8, stream);

  cvt_f32_bf16<<<1024, 256, 0, stream>>>(x, xbf, (int)(XBF_ELEMS / 4));
  const float* Wsrc[3] = { Wz, Wr, Wh };
  for (int gate = 0; gate < 3; gate++)
    for (int l = 0; l < 2; l++)
      cvt_f32_bf16<<<512, 256, 0, stream>>>(Wsrc[gate] + (size_t)l * HD * HD,
                                            wbf + ((size_t)(l * 3 + gate)) * HD * HD,
                                            HD * HD / 4);

  gemm_xg<<<dim3(128, 8, 6), 256, 0, stream>>>(wbf, xbf, xg);

  gru_rec<<<256, 256, 0, stream>>>(h0, Uz, Ur, Uh, bz, br, bh, xg,
                                   (unsigned long long*)(ws + HLN_OFF),
                                   (unsigned long long*)(ws + RLN_OFF),
                                   (unsigned*)(ws + HFLG_OFF),
                                   (unsigned*)(ws + RFLG_OFF),
                                   (float*)d_out);
}

// Round 6
// 4725.558 us; speedup vs baseline: 1.7828x; 1.3363x over previous
//
#include <hip/hip_runtime.h>
#include <stdint.h>

// GRU: L=2, D=H=1024, S=512, B=32.
// Phase 1: xg[s,l,gate,b,h] = x[s,b,:] @ W[l,gate,h,:]^T  (bf16 MFMA GEMM)
// Phase 2: persistent recurrence, 256 single-wave WGs (one 16x16 (g,b) tile
//   each, full K=1024 per wave -> NO intra-WG sync at all). U-slices LDS-
//   resident (96 KB). Cross-WG exchange: untagged bf16 data via agent-scope
//   8B atomic stores, then s_waitcnt vmcnt(0) (release), then one per-
//   producer flag store. Consumers poll 64 flags (1/lane), then bulk-load
//   data with agent-scope loads (coherence point => flag-visible implies
//   data-visible; no retries). Overwrite safety by the flag chain: a WG
//   publishes epoch s+1 only after consuming epoch s from every producer,
//   and every consumer of its epoch-s data published its own epoch-s output
//   (hence finished reading) before this WG could enter epoch s+1.

typedef __attribute__((ext_vector_type(8))) short bf16x8;
typedef __attribute__((ext_vector_type(4))) float f32x4;

#define NL 2
#define SB 32
#define HD 1024
#define SEQ 512

// ---- workspace layout (bytes) ----
#define XG_ELEMS   ((size_t)SEQ*6*SB*HD)
#define XG_OFF     0ull
#define XBF_OFF    (XG_OFF + XG_ELEMS*2)
#define XBF_ELEMS  ((size_t)SEQ*SB*HD)
#define WBF_OFF    (XBF_OFF + XBF_ELEMS*2)
#define WBF_ELEMS  ((size_t)6*HD*HD)
#define HBUF_OFF   (WBF_OFF + WBF_ELEMS*2)      // bf16 h   [L][B][H]
#define HBUF_BYTES ((size_t)NL*SB*HD*2)
#define RBUF_OFF   (HBUF_OFF + HBUF_BYTES)      // bf16 r*h [L][B][H]
#define HFLG_OFF   (RBUF_OFF + HBUF_BYTES)      // 4 grp x 64 prod x 16 u32
#define FLG_WORDS  (4*64*16)
#define RFLG_OFF   (HFLG_OFF + FLG_WORDS*4)
#define WS_NEED    (RFLG_OFF + FLG_WORDS*4)

__device__ __forceinline__ unsigned short f2bf(float f) {
  unsigned int u = __float_as_uint(f);
  u = u + 0x7fffu + ((u >> 16) & 1u);
  return (unsigned short)(u >> 16);
}
__device__ __forceinline__ float bf2f(unsigned int bits) {
  return __uint_as_float(bits << 16);
}
__device__ __forceinline__ f32x4 unpack4(uint2 u) {
  f32x4 v;
  v[0] = bf2f(u.x & 0xffffu); v[1] = bf2f(u.x >> 16);
  v[2] = bf2f(u.y & 0xffffu); v[3] = bf2f(u.y >> 16);
  return v;
}

__device__ __forceinline__ unsigned long long ld_wt(const unsigned long long* p) {
  return __hip_atomic_load(p, __ATOMIC_RELAXED, __HIP_MEMORY_SCOPE_AGENT);
}
__device__ __forceinline__ void st_wt(unsigned long long* p, unsigned long long v) {
  __hip_atomic_store(p, v, __ATOMIC_RELAXED, __HIP_MEMORY_SCOPE_AGENT);
}
__device__ __forceinline__ unsigned ld_flag(const unsigned* p) {
  return __hip_atomic_load(p, __ATOMIC_RELAXED, __HIP_MEMORY_SCOPE_AGENT);
}
__device__ __forceinline__ void st_flag(unsigned* p, unsigned v) {
  __hip_atomic_store(p, v, __ATOMIC_RELAXED, __HIP_MEMORY_SCOPE_AGENT);
}

// ---------------- fp32 -> bf16 convert ----------------
__global__ void cvt_f32_bf16(const float* __restrict__ src,
                             unsigned short* __restrict__ dst, int n4) {
  int i = blockIdx.x * blockDim.x + threadIdx.x;
  int st = gridDim.x * blockDim.x;
  for (; i < n4; i += st) {
    float4 v = ((const float4*)src)[i];
    ushort4 o = { f2bf(v.x), f2bf(v.y), f2bf(v.z), f2bf(v.w) };
    ((ushort4*)dst)[i] = o;
  }
}

// ---------------- phase 1 GEMM ----------------
__global__ __launch_bounds__(256) void gemm_xg(const unsigned short* __restrict__ Wb,
                                               const unsigned short* __restrict__ xb,
                                               unsigned short* __restrict__ xg) {
  __shared__ short As[128 * 32];
  __shared__ short Bs[128 * 32];
  const int lg = blockIdx.z;
  const int m0 = blockIdx.y * 128;
  const int n0 = blockIdx.x * 128;
  const int tid = threadIdx.x, w = tid >> 6, lane = tid & 63;
  const int wm = (w >> 1) * 64, wn = (w & 1) * 64;
  const unsigned short* Ag = Wb + (size_t)lg * HD * HD;

  f32x4 acc[4][4] = {};

  for (int k0 = 0; k0 < HD; k0 += 32) {
    __syncthreads();
#pragma unroll
    for (int i = 0; i < 2; i++) {
      int off = (i * 256 + tid) * 16;
      int rr = off >> 6;
      int cc = (off >> 4) & 3;
      *(uint4*)((char*)As + off) = *(const uint4*)(Ag + (size_t)(m0 + rr) * HD + k0 + cc * 8);
      *(uint4*)((char*)Bs + off) = *(const uint4*)(xb + (size_t)(n0 + rr) * HD + k0 + cc * 8);
    }
    __syncthreads();
    bf16x8 af[4], bf[4];
#pragma unroll
    for (int mi = 0; mi < 4; mi++)
      af[mi] = *(const bf16x8*)&As[(wm + mi * 16 + (lane & 15)) * 32 + ((lane >> 4) << 3)];
#pragma unroll
    for (int ni = 0; ni < 4; ni++)
      bf[ni] = *(const bf16x8*)&Bs[(wn + ni * 16 + (lane & 15)) * 32 + ((lane >> 4) << 3)];
#pragma unroll
    for (int mi = 0; mi < 4; mi++)
#pragma unroll
      for (int ni = 0; ni < 4; ni++)
        acc[mi][ni] = __builtin_amdgcn_mfma_f32_16x16x32_bf16(af[mi], bf[ni], acc[mi][ni], 0, 0, 0);
  }

#pragma unroll
  for (int mi = 0; mi < 4; mi++) {
    int g = m0 + wm + mi * 16 + ((lane >> 4) << 2);
#pragma unroll
    for (int ni = 0; ni < 4; ni++) {
      int n = n0 + wn + ni * 16 + (lane & 15);
      int s = n >> 5, b = n & 31;
      ushort4 o = { f2bf(acc[mi][ni][0]), f2bf(acc[mi][ni][1]),
                    f2bf(acc[mi][ni][2]), f2bf(acc[mi][ni][3]) };
      *(ushort4*)(xg + ((size_t)(s * 6 + lg)) * (SB * HD) + (size_t)b * HD + g) = o;
    }
  }
}

// ---------------- phase 2: recurrence ----------------
// A-frag from swizzled LDS weights: row = lane&15, k = k0 + (lane>>4)*8
__device__ __forceinline__ bf16x8 afrag(const short* wlds, int gate, int lane, int k) {
  int r = lane & 15;
  int kk = k + ((lane >> 4) << 3);
  int ck = (kk >> 3) ^ (r & 7);
  return *(const bf16x8*)&wlds[gate * 16384 + r * HD + (ck << 3)];
}

// release-publish: data store (8B, agent), vmcnt(0), then flag store
__device__ __forceinline__ void publish(unsigned long long* dst, const f32x4 vals,
                                        unsigned* flagword, unsigned tag, int lane) {
  ushort4 o = { f2bf(vals[0]), f2bf(vals[1]), f2bf(vals[2]), f2bf(vals[3]) };
  unsigned long long q; __builtin_memcpy(&q, &o, 8);
  st_wt(dst, q);
  asm volatile("s_waitcnt vmcnt(0)" ::: "memory");   // data visible before flag
  if (lane == 0) st_flag(flagword, tag);
}

// acquire: every lane polls one producer flag
__device__ __forceinline__ void flag_wait64(const unsigned* fgrp, int lane, unsigned tag) {
  bool ok;
  do { ok = (ld_flag(&fgrp[lane * 16]) >= tag); } while (!__all(ok));
}

// bulk-load this lane's B-fragments for the full K=1024 (64 x 8B, untagged)
__device__ __forceinline__ void stage64(const unsigned long long* p, unsigned long long* v) {
#pragma unroll
  for (int kk = 0; kk < 32; kk++) {
    v[2 * kk]     = ld_wt(p + kk * 8);
    v[2 * kk + 1] = ld_wt(p + kk * 8 + 1);
  }
}

__global__ __launch_bounds__(64, 1) void gru_rec(
    const float* __restrict__ h0,
    const float* __restrict__ Uz, const float* __restrict__ Ur, const float* __restrict__ Uh,
    const float* __restrict__ bz, const float* __restrict__ br, const float* __restrict__ bh,
    const unsigned short* __restrict__ xg,
    unsigned long long* __restrict__ hbuf,
    unsigned long long* __restrict__ rbuf,
    unsigned* __restrict__ hflg,
    unsigned* __restrict__ rflg,
    float* __restrict__ out) {
  __shared__ short wlds[3 * 16 * HD];   // 96 KB bf16 U-slices (1 WG/CU)

  const int wg = blockIdx.x;            // 256 WGs, one wave each
  const int l = wg >> 7;
  const int gs = wg & 63;
  const int g0 = gs * 16;
  const int b0 = ((wg >> 6) & 1) * 16;
  const int grp = wg >> 6;              // (l, b-half) group 0..3
  const int lane = threadIdx.x;
  const int col = lane & 15;
  const int sub = lane >> 4;
  const int rb = sub << 2;

  unsigned* hf_g = hflg + grp * 64 * 16;
  unsigned* rf_g = rflg + grp * 64 * 16;

  // ---- load U slices into LDS (bf16, XOR-swizzled 8-elem chunks) ----
  const float* Us[3] = { Uz, Ur, Uh };
#pragma unroll
  for (int gate = 0; gate < 3; gate++) {
    const float* U = Us[gate] + (size_t)l * HD * HD + (size_t)g0 * HD;
    for (int it = 0; it < 32; it++) {
      int chunk = it * 64 + lane;       // 2048 chunks of 8 elems
      int r = chunk >> 7;
      int ck = chunk & 127;
      const float* src = U + (size_t)r * HD + ck * 8;
      float4 a = *(const float4*)src;
      float4 bq = *(const float4*)(src + 4);
      bf16x8 o;
      o[0] = (short)f2bf(a.x); o[1] = (short)f2bf(a.y);
      o[2] = (short)f2bf(a.z); o[3] = (short)f2bf(a.w);
      o[4] = (short)f2bf(bq.x); o[5] = (short)f2bf(bq.y);
      o[6] = (short)f2bf(bq.z); o[7] = (short)f2bf(bq.w);
      int sck = ck ^ (r & 7);
      *(bf16x8*)&wlds[gate * 16384 + r * HD + sck * 8] = o;
    }
  }
  asm volatile("s_waitcnt lgkmcnt(0)" ::: "memory");  // LDS writes done (single wave)

  f32x4 vbz = *(const f32x4*)(bz + l * HD + g0 + rb);
  f32x4 vbr = *(const f32x4*)(br + l * HD + g0 + rb);
  f32x4 vbh = *(const f32x4*)(bh + l * HD + g0 + rb);

  const int brow = l * SB + b0 + col;                 // [L*B] row index
  f32x4 hreg = *(const f32x4*)(h0 + (size_t)brow * HD + g0 + rb);

  unsigned long long* hdst = hbuf + ((size_t)brow << 8) + ((g0 + rb) >> 2);
  unsigned long long* rdst = rbuf + ((size_t)brow << 8) + ((g0 + rb) >> 2);
  const unsigned long long* hp = hbuf + ((size_t)brow << 8) + sub * 2;
  const unsigned long long* rp = rbuf + ((size_t)brow << 8) + sub * 2;

  publish(hdst, hreg, &hf_g[gs * 16], 1u, lane);

  // xg current-step values, prefetched one step ahead
  size_t xb0 = ((size_t)l * 3) * (SB * HD) + (size_t)(b0 + col) * HD + g0 + rb;
  uint2 xzc = *(const uint2*)(xg + xb0);
  uint2 xrc = *(const uint2*)(xg + xb0 + SB * HD);
  uint2 xhc = *(const uint2*)(xg + xb0 + 2 * SB * HD);
  uint2 xzn, xrn, xhn;

  unsigned long long v[64];

  for (int s = 0; s < SEQ; s++) {
    const unsigned tag = (unsigned)(s + 1);

    // ---- phase A: z, r (full K=1024 in this wave) ----
    flag_wait64(hf_g, lane, tag);
    stage64(hp, v);
    f32x4 accz = { 0, 0, 0, 0 }, accr = { 0, 0, 0, 0 };
#pragma unroll
    for (int kk = 0; kk < 32; kk++) {
      union { unsigned long long q[2]; bf16x8 b; } u;
      u.q[0] = v[2 * kk]; u.q[1] = v[2 * kk + 1];
      accz = __builtin_amdgcn_mfma_f32_16x16x32_bf16(afrag(wlds, 0, lane, kk * 32), u.b, accz, 0, 0, 0);
      accr = __builtin_amdgcn_mfma_f32_16x16x32_bf16(afrag(wlds, 1, lane, kk * 32), u.b, accr, 0, 0, 0);
    }
    f32x4 xzf = unpack4(xzc), xrf = unpack4(xrc);
    f32x4 z, rh;
#pragma unroll
    for (int j = 0; j < 4; j++) {
      float za = xzf[j] + vbz[j] + accz[j];
      float ra = xrf[j] + vbr[j] + accr[j];
      z[j] = 1.f / (1.f + __expf(-za));
      rh[j] = (1.f / (1.f + __expf(-ra))) * hreg[j];
    }
    publish(rdst, rh, &rf_g[gs * 16], tag, lane);

    // prefetch next step's xg (overlaps phase-B exchange latency)
    {
      int sn = (s + 1 < SEQ) ? s + 1 : s;
      size_t xbn = ((size_t)sn * 6 + l * 3) * (SB * HD) + (size_t)(b0 + col) * HD + g0 + rb;
      xzn = *(const uint2*)(xg + xbn);
      xrn = *(const uint2*)(xg + xbn + SB * HD);
      xhn = *(const uint2*)(xg + xbn + 2 * SB * HD);
    }

    // ---- phase B: hh, h update ----
    flag_wait64(rf_g, lane, tag);
    stage64(rp, v);
    f32x4 acch = { 0, 0, 0, 0 };
#pragma unroll
    for (int kk = 0; kk < 32; kk++) {
      union { unsigned long long q[2]; bf16x8 b; } u;
      u.q[0] = v[2 * kk]; u.q[1] = v[2 * kk + 1];
      acch = __builtin_amdgcn_mfma_f32_16x16x32_bf16(afrag(wlds, 2, lane, kk * 32), u.b, acch, 0, 0, 0);
    }
    f32x4 xhf = unpack4(xhc);
#pragma unroll
    for (int j = 0; j < 4; j++) {
      float ha = xhf[j] + vbh[j] + acch[j];
      float e = __expf(2.f * ha);                    // tanh via exp
      float hh = 1.f - 2.f / (e + 1.f);
      hreg[j] = (1.f - z[j]) * hreg[j] + z[j] * hh;
    }
    publish(hdst, hreg, &hf_g[gs * 16], tag + 1, lane);

    if (l == 1)      // output stream is LAST layer only
      *(f32x4*)(out + (size_t)s * (SB * HD) + (size_t)(b0 + col) * HD + g0 + rb) = hreg;
    if (s == SEQ - 1)
      *(f32x4*)(out + (size_t)SEQ * SB * HD + (size_t)brow * HD + g0 + rb) = hreg;

    xzc = xzn; xrc = xrn; xhc = xhn;
  }
}

extern "C" void kernel_launch(void* const* d_in, const int* in_sizes, int n_in,
                              void* d_out, int out_size, void* d_ws, size_t ws_size,
                              hipStream_t stream) {
  const float* x  = (const float*)d_in[0];
  const float* h0 = (const float*)d_in[1];
  const float* Wz = (const float*)d_in[2];
  const float* Wr = (const float*)d_in[3];
  const float* Wh = (const float*)d_in[4];
  const float* Uz = (const float*)d_in[5];
  const float* Ur = (const float*)d_in[6];
  const float* Uh = (const float*)d_in[7];
  const float* bz = (const float*)d_in[8];
  const float* br = (const float*)d_in[9];
  const float* bh = (const float*)d_in[10];

  char* ws = (char*)d_ws;
  unsigned short* xg  = (unsigned short*)(ws + XG_OFF);
  unsigned short* xbf = (unsigned short*)(ws + XBF_OFF);
  unsigned short* wbf = (unsigned short*)(ws + WBF_OFF);

  // clear flags (replay safety; data buffers need no clearing — untagged,
  // gated by flags which are reset here)
  hipMemsetAsync(ws + HFLG_OFF, 0, FLG_WORDS * 8, stream);

  cvt_f32_bf16<<<1024, 256, 0, stream>>>(x, xbf, (int)(XBF_ELEMS / 4));
  const float* Wsrc[3] = { Wz, Wr, Wh };
  for (int gate = 0; gate < 3; gate++)
    for (int l = 0; l < 2; l++)
      cvt_f32_bf16<<<512, 256, 0, stream>>>(Wsrc[gate] + (size_t)l * HD * HD,
                                            wbf + ((size_t)(l * 3 + gate)) * HD * HD,
                                            HD * HD / 4);

  gemm_xg<<<dim3(128, 8, 6), 256, 0, stream>>>(wbf, xbf, xg);

  gru_rec<<<256, 64, 0, stream>>>(h0, Uz, Ur, Uh, bz, br, bh, xg,
                                  (unsigned long long*)(ws + HBUF_OFF),
                                  (unsigned long long*)(ws + RBUF_OFF),
                                  (unsigned*)(ws + HFLG_OFF),
                                  (unsigned*)(ws + RFLG_OFF),
                                  (float*)d_out);
}